// Round 6
// baseline (464.470 us; speedup 1.0000x reference)
//
#include <hip/hip_runtime.h>
#include <math.h>

// Capsule routing B=32, N=1024(j), D=256(k), NC=32(i), DC=64(d).
// Round-15: launch gaps (~16us x 5 = 60% of runtime, per R0/R3 arithmetic)
// are the bottleneck; all kernel-internal changes were neutral (R1/R2/R5).
// ONE fused kernel k_big, 512 blocks (b*16+p) x 1024 thr, with per-b
// 16-block soft barriers (NOT grid-wide: cg::grid.sync measured ~60us each
// in R5). Co-residency guaranteed: 77.6KB LDS + launch_bounds(1024,8) ->
// exactly 2 blocks/CU x 256 CU = 512. Stages:
//   S0 stage U->s_U bf16 (persists BOTH passes; U read from HBM once)
//      + colsum partials t0p       | bar(b,0)
//   S1 sv0 distributed: block p computes capsule il=p (W traffic
//      distributed across siblings, not duplicated) -> wbt      | bar(b,1)
//   S2 pass0: D-MFMA -> logits (kept in 2 VGPRs) -> exp -> T-MFMA
//      -> unsafeAtomicAdd into t,sef (R3-verified coherent)     | bar(b,2)
//   S3 sv1 (reads t, re-zeros for pass1) -> wbt                 | bar(b,3)
//   S4 pass1 (s_U still resident, logits += VGPR)               | bar(b,4)
//   S5 sv2 -> out
// Cross-block data: unsafeAtomicAdd accumulators + relaxed-agent atomic
// load/store (R3-verified); barrier = threadfence + acq-rel counter.
// k_init = W transpose + t/sef/ctr zeroing only. 2 launches, 1 gap.

typedef short v8s __attribute__((ext_vector_type(8)));
typedef short v4s __attribute__((ext_vector_type(4)));
typedef float v4f __attribute__((ext_vector_type(4)));

__device__ __forceinline__ unsigned short f2bf(float x) {
    unsigned u = __float_as_uint(x);
    u = u + 0x7fffu + ((u >> 16) & 1u);
    return (unsigned short)(u >> 16);
}
__device__ __forceinline__ float bf2f(unsigned short h) {
    return __uint_as_float(((unsigned)h) << 16);
}
__device__ __forceinline__ float ald(const float* p) {
    return __hip_atomic_load(p, __ATOMIC_RELAXED, __HIP_MEMORY_SCOPE_AGENT);
}
__device__ __forceinline__ void ast(float* p, float v) {
    __hip_atomic_store(p, v, __ATOMIC_RELAXED, __HIP_MEMORY_SCOPE_AGENT);
}
__device__ __forceinline__ unsigned long long ald64(const void* p) {
    return __hip_atomic_load((const unsigned long long*)p,
                             __ATOMIC_RELAXED, __HIP_MEMORY_SCOPE_AGENT);
}
__device__ __forceinline__ void ast64(void* p, unsigned long long v) {
    __hip_atomic_store((unsigned long long*)p, v,
                       __ATOMIC_RELAXED, __HIP_MEMORY_SCOPE_AGENT);
}

// 16-block barrier over the p-siblings of batch b. All 512 blocks are
// co-resident (2/CU exact), so the spin cannot deadlock.
__device__ __forceinline__ void bar_b(int* ctr, int b, int phase, int tid) {
    __syncthreads();                       // drains this block's mem ops
    if (tid == 0) {
        __threadfence();                   // device-scope release
        int* c = ctr + (b << 3) + phase;
        __hip_atomic_fetch_add(c, 1, __ATOMIC_ACQ_REL,
                               __HIP_MEMORY_SCOPE_AGENT);
        while (__hip_atomic_load(c, __ATOMIC_ACQUIRE,
                                 __HIP_MEMORY_SCOPE_AGENT) < 16)
            __builtin_amdgcn_s_sleep(2);
        __threadfence();                   // device-scope acquire
    }
    __syncthreads();
}

// ---------------------------------------------------------------------------
// k_init: blocks 0..127 transpose W -> WT; blocks 128..191 zero t/sef/ctr.
__global__ __launch_bounds__(256) void k_init(const float* __restrict__ W,
                                              float* __restrict__ WT,
                                              float* __restrict__ t,
                                              float* __restrict__ sef,
                                              int* __restrict__ ctr) {
    int bid = blockIdx.x, tid = threadIdx.x;
    if (bid < 128) {
        __shared__ float tile[64 * 65];
        int k0 = (bid >> 5) << 6, c0 = (bid & 31) << 6;
        int cc = tid & 63, g4 = tid >> 6;
        #pragma unroll
        for (int r = 0; r < 16; ++r) {
            int kk = (g4 << 4) + r;
            tile[kk * 65 + cc] = W[(k0 + kk) * 2048 + c0 + cc];
        }
        __syncthreads();
        int kk = tid & 63;
        #pragma unroll
        for (int r = 0; r < 16; ++r) {
            int c = (g4 << 4) + r;
            WT[(c0 + c) * 256 + k0 + kk] = tile[kk * 65 + c];
        }
    } else {
        int z = bid - 128;                  // 0..63
        #pragma unroll
        for (int r = 0; r < 16; ++r)
            t[(z << 12) + (r << 8) + tid] = 0.f;
        if (z == 0) {
            #pragma unroll
            for (int r = 0; r < 4; ++r) sef[(r << 8) + tid] = 0.f;
            if (tid < 256) ctr[tid] = 0;
        }
    }
}

// ---------------------------------------------------------------------------
// sv interlude: block (b,p) computes capsule il=p for both g2 groups.
// mode 0: t row from t0p colsums, sef=1. mode 1: t row from atomic t accum
// (re-zeroed unless final). final: write v -> out, skip w-phase.
__device__ __forceinline__ void sv_block(
    float* s_red, float* s_v, float* s_scal,
    int b, int p, int tid, int wv, int lane,
    const float* __restrict__ t0p, float* __restrict__ t,
    float* __restrict__ sef, const float* __restrict__ W,
    const float* __restrict__ WT, short* __restrict__ wbt_h,
    short* __restrict__ wbt_l, float* __restrict__ out,
    int mode, int final_out)
{
    #pragma unroll
    for (int g2 = 0; g2 < 2; ++g2) {
        const int iG = (g2 << 4) + p;
        const int bg = (b << 1) | g2;
        // t row (256 k) into s_red[0..255]
        if (mode == 0) {
            if (tid < 256) {
                float a = 0.f;
                #pragma unroll
                for (int q = 0; q < 16; ++q)
                    a += ald(&t0p[(b << 12) + (q << 8) + tid]);
                s_red[tid] = a;
            }
            if (tid == 0) s_scal[0] = 1.0f;
        } else {
            if (tid < 256) {
                const int o = (((bg << 4) + p) << 8) + tid;
                s_red[tid] = ald(&t[o]);
                if (!final_out) ast(&t[o], 0.f);   // re-zero for next pass
            }
            if (tid == 0) {
                s_scal[0] = ald(&sef[(bg << 4) + p]);
                if (!final_out) ast(&sef[(bg << 4) + p], 0.f);
            }
        }
        __syncthreads();
        // s-phase: lane=d, wave=16-k chunk; spart @ s_red[256..1279]
        {
            const float* Wc = W + (iG << 6) + lane;
            float sp = 0.f;
            #pragma unroll
            for (int kk = 0; kk < 16; ++kk) {
                int k = (wv << 4) + kk;
                sp += s_red[k] * Wc[k * 2048];
            }
            s_red[256 + (wv << 6) + lane] = sp;
        }
        __syncthreads();
        if (tid < 64) {
            float sv = 0.f;
            #pragma unroll
            for (int q = 0; q < 16; ++q) sv += s_red[256 + (q << 6) + tid];
            float n2 = sv * sv;
            #pragma unroll
            for (int m = 1; m < 64; m <<= 1) n2 += __shfl_xor(n2, m, 64);
            float sf = s_scal[0];
            float vv = sv * rsqrtf(n2 + 1e-7f * sf * sf);
            if (final_out) out[(b << 11) + (iG << 6) + tid] = vv;
            else s_v[tid] = vv;
        }
        __syncthreads();
        if (final_out) continue;
        // w-phase: wave=dq (4 d's), lane=k4; wpart overlays s_red (dead)
        {
            const float4* WT4 = (const float4*)WT;
            v4f wp = {0.f, 0.f, 0.f, 0.f};
            #pragma unroll
            for (int e = 0; e < 4; ++e) {
                int d = (wv << 2) + e;
                float vd = s_v[d];
                float4 wt = WT4[(((iG << 6) + d) << 6) + lane];
                wp.x += vd * wt.x; wp.y += vd * wt.y;
                wp.z += vd * wt.z; wp.w += vd * wt.w;
            }
            ((v4f*)s_red)[(wv << 6) + lane] = wp;
        }
        __syncthreads();
        if (tid < 64) {
            v4f w = {0.f, 0.f, 0.f, 0.f};
            #pragma unroll
            for (int q = 0; q < 16; ++q) w += ((v4f*)s_red)[(q << 6) + tid];
            float wv4[4] = {w.x, w.y, w.z, w.w};
            unsigned short wh[4], wl[4];
            #pragma unroll
            for (int e = 0; e < 4; ++e) {
                wh[e] = f2bf(wv4[e]);
                wl[e] = f2bf(wv4[e] - bf2f(wh[e]));
            }
            union { v4s s; unsigned long long u; } ch, cl;
            ch.s = (v4s){(short)wh[0], (short)wh[1], (short)wh[2], (short)wh[3]};
            cl.s = (v4s){(short)wl[0], (short)wl[1], (short)wl[2], (short)wl[3]};
            const int bsx = (((bg << 4) + p) << 8) + (tid << 2);
            ast64(&wbt_h[bsx], ch.u);
            ast64(&wbt_l[bsx], cl.u);
        }
        __syncthreads();
    }
}

// ---------------------------------------------------------------------------
// pass body (R5-verified g2-merged k_pass): stage wbt -> D -> logits/exp ->
// T -> unsafeAtomicAdd t/sef. Logits kept in vlog[2] VGPRs across passes.
__device__ __forceinline__ void pass_block(
    short* s_U, short* s_wh, short* s_wl, short* s_eh, short* s_el,
    float* s_red, float* s_sefp,
    int b, int tid, int wv, int lane, int quad, int nn,
    const short* __restrict__ wbt_h, const short* __restrict__ wbt_l,
    float* __restrict__ t, float* __restrict__ sef,
    float* vlog, int pass)
{
    const int mt2 = wv & 3, jq = wv >> 2;
    const int rr = (jq << 2) + quad;
    const int jloc = (mt2 << 4) + rr;
    #pragma unroll
    for (int g2 = 0; g2 < 2; ++g2) {
        const int bg = (b << 1) | g2;
        if (tid < 512) {
            int row = tid >> 5, seg = tid & 31;
            int gidx = (((bg << 4) + row) << 8) + (seg << 3);
            unsigned long long h0 = ald64(&wbt_h[gidx]);
            unsigned long long h1 = ald64(&wbt_h[gidx + 4]);
            unsigned long long l0 = ald64(&wbt_l[gidx]);
            unsigned long long l1 = ald64(&wbt_l[gidx + 4]);
            *(unsigned long long*)&s_wh[row * 264 + (seg << 3)]     = h0;
            *(unsigned long long*)&s_wh[row * 264 + (seg << 3) + 4] = h1;
            *(unsigned long long*)&s_wl[row * 264 + (seg << 3)]     = l0;
            *(unsigned long long*)&s_wl[row * 264 + (seg << 3) + 4] = l1;
        }
        __syncthreads();
        // phase D: wave = (mt = j-tile, kq = K-quarter)
        {
            const int mt = wv & 3, kq = wv >> 2;
            v4f dacc = {0.f, 0.f, 0.f, 0.f};
            #pragma unroll
            for (int c = 0; c < 2; ++c) {
                int kb = (kq << 6) + (c << 5) + (quad << 3);
                v8s a  = *(const v8s*)&s_U[((mt << 4) + nn) * 268 + kb];
                v8s bh = *(const v8s*)&s_wh[nn * 264 + kb];
                v8s bl = *(const v8s*)&s_wl[nn * 264 + kb];
                dacc = __builtin_amdgcn_mfma_f32_16x16x32_bf16(a, bh, dacc, 0, 0, 0);
                dacc = __builtin_amdgcn_mfma_f32_16x16x32_bf16(a, bl, dacc, 0, 0, 0);
            }
            #pragma unroll
            for (int r = 0; r < 4; ++r)
                s_red[wv * 320 + ((quad << 2) + r) * 20 + nn] = dacc[r];
        }
        __syncthreads();
        // K-reduce + logits (VGPR across passes) + exp + sef partials
        {
            float val = pass ? vlog[g2] : 0.f;
            #pragma unroll
            for (int kq = 0; kq < 4; ++kq)
                val += s_red[((kq << 2) + mt2) * 320 + rr * 20 + nn];
            if (!pass) vlog[g2] = val;
            float e = __expf(val);
            unsigned short eh = f2bf(e);
            s_eh[nn * 72 + jloc] = (short)eh;
            s_el[nn * 72 + jloc] = (short)f2bf(e - bf2f(eh));
            float se = e;
            se += __shfl_xor(se, 16, 64);
            se += __shfl_xor(se, 32, 64);
            if (lane < 16) s_sefp[(wv << 4) + lane] = se;
        }
        __syncthreads();
        // phase T: wave = 16-k N-tile; accumulate into global t via atomics
        {
            v4f tacc = {0.f, 0.f, 0.f, 0.f};
            const int k0 = wv << 4;
            #pragma unroll
            for (int jc = 0; jc < 2; ++jc) {
                v8s aeh = *(const v8s*)&s_eh[nn * 72 + (jc << 5) + (quad << 3)];
                v8s ael = *(const v8s*)&s_el[nn * 72 + (jc << 5) + (quad << 3)];
                short bu[8];
                #pragma unroll
                for (int jj = 0; jj < 8; ++jj)
                    bu[jj] = s_U[((jc << 5) + (quad << 3) + jj) * 268 + k0 + nn];
                v8s bf = (v8s){bu[0], bu[1], bu[2], bu[3],
                               bu[4], bu[5], bu[6], bu[7]};
                tacc = __builtin_amdgcn_mfma_f32_16x16x32_bf16(aeh, bf, tacc, 0, 0, 0);
                tacc = __builtin_amdgcn_mfma_f32_16x16x32_bf16(ael, bf, tacc, 0, 0, 0);
            }
            #pragma unroll
            for (int r = 0; r < 4; ++r) {
                int i = (quad << 2) + r;
                unsafeAtomicAdd(&t[(((bg << 4) + i) << 8) + k0 + nn], tacc[r]);
            }
        }
        if (tid < 16) {
            float ss = 0.f;
            #pragma unroll
            for (int w = 0; w < 16; ++w) ss += s_sefp[(w << 4) + tid];
            unsafeAtomicAdd(&sef[(bg << 4) + tid], ss);
        }
        __syncthreads();
    }
}

// ---------------------------------------------------------------------------
__global__ __launch_bounds__(1024, 8) void k_big(
    const float* __restrict__ U, const float* __restrict__ W,
    const float* __restrict__ WT, float* __restrict__ t0p,
    float* __restrict__ t, float* __restrict__ sef,
    short* __restrict__ wbt_h, short* __restrict__ wbt_l,
    int* __restrict__ ctr, float* __restrict__ out)
{
    __shared__ short s_U[64 * 268];      // 34,304 B, persists S0..S4
    __shared__ short s_wh[16 * 264];     // 8,448
    __shared__ short s_wl[16 * 264];     // 8,448
    __shared__ short s_eh[16 * 72];      // 2,304
    __shared__ short s_el[16 * 72];      // 2,304
    __shared__ __align__(16) float s_red[16 * 320];   // 20,480 scratch
    __shared__ float s_sefp[16 * 16];    // 1,024
    __shared__ __align__(16) float s_v[64];
    __shared__ float s_scal[2];          // total 77,576 B -> 2 blocks/CU

    const int tid = threadIdx.x, wv = tid >> 6, lane = tid & 63;
    const int quad = lane >> 4, nn = lane & 15;
    const int blk = blockIdx.x;
    const int b = blk >> 4, p = blk & 15;      // 16 p-siblings per b
    const int rowbase = (b << 10) + (p << 6);
    float vlog[2];

    // ---- S0: stage U -> s_U bf16 + colsum partials -> t0p ----
    {
        v4f* cp4 = (v4f*)s_red;                 // [16][64] column partials
        const float4* U4 = (const float4*)U;
        int col = tid & 63, row0 = tid >> 6;
        v4f psum = {0.f, 0.f, 0.f, 0.f};
        #pragma unroll
        for (int q = 0; q < 4; ++q) {
            float4 g = U4[(rowbase + row0 + (q << 4)) * 64 + col];
            psum.x += g.x; psum.y += g.y; psum.z += g.z; psum.w += g.w;
            *(v4s*)&s_U[(row0 + (q << 4)) * 268 + (col << 2)] =
                (v4s){(short)f2bf(g.x), (short)f2bf(g.y),
                      (short)f2bf(g.z), (short)f2bf(g.w)};
        }
        cp4[(row0 << 6) + col] = psum;
        __syncthreads();
        if (tid < 256) {
            const float* cp = (const float*)cp4;
            float acc = 0.f;
            #pragma unroll
            for (int r0 = 0; r0 < 16; ++r0) acc += cp[(r0 << 8) + tid];
            ast(&t0p[(b << 12) + (p << 8) + tid], acc * (1.0f / 1024.0f));
        }
    }
    bar_b(ctr, b, 0, tid);

    // ---- S1: sv0 ----
    sv_block(s_red, s_v, s_scal, b, p, tid, wv, lane,
             t0p, t, sef, W, WT, wbt_h, wbt_l, out, 0, 0);
    bar_b(ctr, b, 1, tid);

    // ---- S2: pass 0 ----
    pass_block(s_U, s_wh, s_wl, s_eh, s_el, s_red, s_sefp,
               b, tid, wv, lane, quad, nn, wbt_h, wbt_l, t, sef, vlog, 0);
    bar_b(ctr, b, 2, tid);

    // ---- S3: sv1 (reads + re-zeros t/sef) ----
    sv_block(s_red, s_v, s_scal, b, p, tid, wv, lane,
             t0p, t, sef, W, WT, wbt_h, wbt_l, out, 1, 0);
    bar_b(ctr, b, 3, tid);

    // ---- S4: pass 1 (s_U still resident) ----
    pass_block(s_U, s_wh, s_wl, s_eh, s_el, s_red, s_sefp,
               b, tid, wv, lane, quad, nn, wbt_h, wbt_l, t, sef, vlog, 1);
    bar_b(ctr, b, 4, tid);

    // ---- S5: sv2 -> out ----
    sv_block(s_red, s_v, s_scal, b, p, tid, wv, lane,
             t0p, t, sef, W, WT, wbt_h, wbt_l, out, 1, 1);
}

// ---------------------------------------------------------------------------
extern "C" void kernel_launch(void* const* d_in, const int* in_sizes, int n_in,
                              void* d_out, int out_size, void* d_ws, size_t ws_size,
                              hipStream_t stream) {
    const float* U = (const float*)d_in[0];   // [32,1024,256]
    const float* W = (const float*)d_in[1];   // [256,2048]
    float* out = (float*)d_out;               // [32,32,64]
    float* ws = (float*)d_ws;

    float* t0p   = ws;                  // [32][16][256]  = 131,072 f
    float* WT    = t0p + 131072;        // [2048][256]    = 524,288 f
    float* t     = WT + 524288;         // [64][16][256]  = 262,144 f (atomic)
    float* sef   = t + 262144;          // [64][16]       =   1,024 f (atomic)
    short* wbt_h = (short*)(sef + 1024);    // [64][16][256] shorts
    short* wbt_l = wbt_h + 262144;
    int*   ctr   = (int*)(wbt_l + 262144);  // [32][8] barrier counters

    k_init<<<192, 256, 0, stream>>>(W, WT, t, sef, ctr);
    k_big<<<512, 1024, 0, stream>>>(U, W, WT, t0p, t, sef,
                                    wbt_h, wbt_l, ctr, out);
}

// Round 7
// 133.125 us; speedup vs baseline: 3.4890x; 3.4890x over previous
//
#include <hip/hip_runtime.h>
#include <math.h>

// Capsule routing B=32, N=1024(j), D=256(k), NC=32(i), DC=64(d). Factored
// (no u_hat), MFMA 16x16x32 bf16:
//   delta[j,i] = U[b,j,:].w[:,i]; e = exp(logit); t[i,k] = sum_j e[i,j] U[j,k]
//   s = tW_i; v = s*rsqrt(||s||^2+eps*sef^2); w = W_i v   (k_sv, fp32)
// History: R1 Ubf (neutral), R2 atomics (-), R3 tail-fusion (--), R4/R5 coop
// (grid.sync ~60us each, dead), R6 soft-barriers (fences kill L2, dead).
// Inter-kernel fusion is closed; traffic is not the bottleneck.
// Round-16: attack k_pass's LATENCY structure (MfmaUtil ~1%, VALUBusy ~6%
// in every profile = all pipes idle, 7 barriers + K-split LDS round-trip):
//   - wave = (j-tile, g2) computes delta with FULL K=256 in one 16-MFMA
//     register chain: no s_red, no K-reduce, no reduce barrier
//   - logits + exp computed directly on the MFMA accumulator (VGPRs)
//   - both g2 groups concurrent (8 D-waves, 16 T-waves), not serial
//   - barriers per k_pass: 7 -> 2; s_red (20KB) deleted
// k_init (t0p colsum + W^T, no Ubf) and k_sv (R0-proven) unchanged.

typedef short v8s __attribute__((ext_vector_type(8)));
typedef short v4s __attribute__((ext_vector_type(4)));
typedef float v4f __attribute__((ext_vector_type(4)));

__device__ __forceinline__ unsigned short f2bf(float x) {
    unsigned u = __float_as_uint(x);
    u = u + 0x7fffu + ((u >> 16) & 1u);
    return (unsigned short)(u >> 16);
}
__device__ __forceinline__ float bf2f(unsigned short h) {
    return __uint_as_float(((unsigned)h) << 16);
}

// ---------------------------------------------------------------------------
// k_init: bid<512: colsum partials t0p[b][q][k] (iter-0 uniform softmax);
//         bid>=512: transpose W (256x2048) -> WT (2048x256).
__global__ __launch_bounds__(256) void k_init(const float* __restrict__ U,
                                              const float* __restrict__ W,
                                              float* __restrict__ t0p,
                                              float* __restrict__ WT) {
    int bid = blockIdx.x, tid = threadIdx.x;
    if (bid < 512) {
        int b = bid >> 4, q = bid & 15;
        const float* Up = U + (((b << 10) + (q << 6)) << 8) + tid;
        float acc = 0.f;
        #pragma unroll 16
        for (int jl = 0; jl < 64; ++jl) acc += Up[jl << 8];
        t0p[(b << 12) + (q << 8) + tid] = acc * (1.0f / 1024.0f);
    } else {
        __shared__ float tile[64 * 65];
        int tix = bid - 512;                 // 0..127
        int k0 = (tix >> 5) << 6, c0 = (tix & 31) << 6;
        int cc = tid & 63, g4 = tid >> 6;
        #pragma unroll
        for (int r = 0; r < 16; ++r) {
            int kk = (g4 << 4) + r;
            tile[kk * 65 + cc] = W[(k0 + kk) * 2048 + c0 + cc];
        }
        __syncthreads();
        int kk = tid & 63;
        #pragma unroll
        for (int r = 0; r < 16; ++r) {
            int c = (g4 << 4) + r;
            WT[(c0 + c) * 256 + k0 + kk] = tile[kk * 65 + c];
        }
    }
}

// ---------------------------------------------------------------------------
// k_sv (R0-proven): per (b,iG): t[k] = sum of 16 partials; s = tW_i;
// v = squash(.,sef); w = W_i v -> wbt hi/lo. grid 1024, block 256.
__global__ __launch_bounds__(256) void k_sv(const float* __restrict__ t0p,
                                            const float* __restrict__ tpart,
                                            const float* __restrict__ sefpart,
                                            const float* __restrict__ W,
                                            const float* __restrict__ WT,
                                            short* __restrict__ wbt_h,
                                            short* __restrict__ wbt_l,
                                            float* __restrict__ out,
                                            int mode, int writeOut) {
    __shared__ float t_lds[256];
    __shared__ float spart[256];
    __shared__ __align__(16) float v_lds[64];
    __shared__ __align__(16) v4f spartw[256];
    __shared__ float sefv_s;
    int bid = blockIdx.x, tid = threadIdx.x;
    int b = bid >> 5, iG = bid & 31;
    int bg = (b << 1) | (iG >> 4), il = iG & 15;

    float acc = 0.f;
    if (mode == 0) {
        const float* tb = t0p + (b << 12) + tid;
        #pragma unroll
        for (int q = 0; q < 16; ++q) acc += tb[q << 8];
        if (tid == 0) sefv_s = 1.0f;
    } else {
        const float* tb = tpart + (((bg << 4) + il) << 8) + tid;
        #pragma unroll
        for (int p = 0; p < 16; ++p) acc += tb[p << 18];  // stride 64*16*256
        if (tid == 0) {
            float s = 0.f;
            #pragma unroll
            for (int p = 0; p < 16; ++p) s += sefpart[(p << 10) + (bg << 4) + il];
            sefv_s = s;
        }
    }
    t_lds[tid] = acc;
    __syncthreads();

    // s-phase: (d = tid&63, kq = tid>>6), coalesced 256B W reads
    int d = tid & 63, kq = tid >> 6;
    const float* Wc = W + ((kq << 6) * 2048) + (iG << 6) + d;
    float s = 0.f;
    #pragma unroll 4
    for (int kk = 0; kk < 64; ++kk)
        s += t_lds[(kq << 6) + kk] * Wc[kk * 2048];
    spart[tid] = s;
    __syncthreads();

    if (tid < 64) {
        float sv = spart[tid] + spart[tid + 64] + spart[tid + 128] + spart[tid + 192];
        float n2 = sv * sv;
        #pragma unroll
        for (int m = 1; m < 64; m <<= 1) n2 += __shfl_xor(n2, m, 64);
        float sf = sefv_s;
        float v = sv * rsqrtf(n2 + 1e-7f * sf * sf);
        v_lds[tid] = v;
        if (writeOut) out[(bid << 6) + tid] = v;
    }
    __syncthreads();
    if (writeOut) return;

    // w-phase: (k4 = tid&63, dq = tid>>6), WT gives coalesced 1KB/instr reads
    int k4 = tid & 63, dq = tid >> 6;
    const float4* WT4 = (const float4*)WT;
    v4f wp = {0.f, 0.f, 0.f, 0.f};
    #pragma unroll
    for (int dd = 0; dd < 16; ++dd) {
        float vv = v_lds[(dq << 4) + dd];
        float4 wt = WT4[((iG << 6) + (dq << 4) + dd) * 64 + k4];
        wp.x += vv * wt.x; wp.y += vv * wt.y; wp.z += vv * wt.z; wp.w += vv * wt.w;
    }
    spartw[(dq << 6) + k4] = wp;
    __syncthreads();
    if (tid < 64) {
        v4f w = spartw[tid] + spartw[64 + tid] + spartw[128 + tid] + spartw[192 + tid];
        float wv4[4] = {w.x, w.y, w.z, w.w};
        unsigned short wh[4], wl[4];
        #pragma unroll
        for (int e = 0; e < 4; ++e) {
            wh[e] = f2bf(wv4[e]);
            wl[e] = f2bf(wv4[e] - bf2f(wh[e]));
        }
        int base = (((bg << 4) + il) << 8) + (tid << 2);
        *(v4s*)&wbt_h[base] = (v4s){(short)wh[0], (short)wh[1], (short)wh[2], (short)wh[3]};
        *(v4s*)&wbt_l[base] = (v4s){(short)wl[0], (short)wl[1], (short)wl[2], (short)wl[3]};
    }
}

// ---------------------------------------------------------------------------
// k_pass v6: grid 512 (b = blk&31, p = blk>>5), block 1024 = 16 waves.
// LDS 77,824 B -> 2 blocks/CU.
//   stage U (f32->bf16) + stage w for BOTH g2     | barrier
//   phase D: waves 0-7 = (jt, g2): full-K=256 register chain (16 MFMA),
//     logits+exp on the accumulator in VGPRs, bmatg rw, e->s_eh/s_el,
//     sef 16-j partial via shfl -> s_sefp          | barrier
//   phase T: 16 waves = (g2, kt2): 2 k-tiles each (8 MFMA) -> tpart;
//     lanes<32 reduce s_sefp -> sefpart. No trailing barrier.
__global__ __launch_bounds__(1024, 8) void k_pass(const float* __restrict__ U,
                                                  const short* __restrict__ wbt_h,
                                                  const short* __restrict__ wbt_l,
                                                  float* __restrict__ bmatg,
                                                  float* __restrict__ tpart_out,
                                                  float* __restrict__ sefpart_out,
                                                  int addold) {
    __shared__ short s_U[64 * 268];        // 34,304 B [j][k] pad 12
    __shared__ short s_wh[2 * 16 * 264];   // 16,896 [g2][i][k] pad 8
    __shared__ short s_wl[2 * 16 * 264];   // 16,896
    __shared__ short s_eh[2 * 16 * 72];    // 4,608  [g2][i][j] pad 8
    __shared__ short s_el[2 * 16 * 72];    // 4,608
    __shared__ float s_sefp[8 * 16];       // 512  [(g2*4+jt)][i]  tot 77,824

    const int tid = threadIdx.x, wv = tid >> 6, lane = tid & 63;
    const int quad = lane >> 4, nn = lane & 15;
    const int blk = blockIdx.x;
    const int b = blk & 31, p = blk >> 5;
    const int rowbase = (b << 10) + (p << 6);

    // ---- stage U (f32 -> bf16) and w (both g2) ----
    {
        const float4* U4 = (const float4*)U;
        int col = tid & 63, row0 = tid >> 6;
        float4 g[4];
        #pragma unroll
        for (int q = 0; q < 4; ++q)
            g[q] = U4[(rowbase + row0 + (q << 4)) * 64 + col];
        #pragma unroll
        for (int q = 0; q < 4; ++q)
            *(v4s*)&s_U[(row0 + (q << 4)) * 268 + (col << 2)] =
                (v4s){(short)f2bf(g[q].x), (short)f2bf(g[q].y),
                      (short)f2bf(g[q].z), (short)f2bf(g[q].w)};
        // w: row = tid>>5 (0..31 = g2*16+il), seg = tid&31
        int row = tid >> 5, seg = tid & 31;
        int gidx = (((b << 5) + row) << 8) + (seg << 3);
        int lidx = (row >> 4) * 4224 + (row & 15) * 264 + (seg << 3);
        *(v8s*)&s_wh[lidx] = *(const v8s*)(wbt_h + gidx);
        *(v8s*)&s_wl[lidx] = *(const v8s*)(wbt_l + gidx);
    }
    __syncthreads();

    // ---- phase D: waves 0-7 = (jt = wv&3, g2 = wv>>2), full K=256 ----
    if (wv < 8) {
        const int jt = wv & 3, g2 = wv >> 2;
        const int bg = (b << 1) | g2;
        v4f dacc = {0.f, 0.f, 0.f, 0.f};
        #pragma unroll
        for (int c = 0; c < 8; ++c) {
            int kb = (c << 5) + (quad << 3);
            v8s a  = *(const v8s*)&s_U[((jt << 4) + nn) * 268 + kb];
            v8s bh = *(const v8s*)&s_wh[g2 * 4224 + nn * 264 + kb];
            v8s bl = *(const v8s*)&s_wl[g2 * 4224 + nn * 264 + kb];
            dacc = __builtin_amdgcn_mfma_f32_16x16x32_bf16(a, bh, dacc, 0, 0, 0);
            dacc = __builtin_amdgcn_mfma_f32_16x16x32_bf16(a, bl, dacc, 0, 0, 0);
        }
        // logits + exp directly on the accumulator
        float se = 0.f;
        #pragma unroll
        for (int r = 0; r < 4; ++r) {
            int jloc = (jt << 4) + (quad << 2) + r;
            int ga = (((bg << 10) + (p << 6) + jloc) << 4) + nn;
            float val = dacc[r];
            if (addold) val += bmatg[ga];
            else bmatg[ga] = val;
            float e = __expf(val);
            unsigned short eh = f2bf(e);
            s_eh[g2 * 1152 + nn * 72 + jloc] = (short)eh;
            s_el[g2 * 1152 + nn * 72 + jloc] = (short)f2bf(e - bf2f(eh));
            se += e;
        }
        se += __shfl_xor(se, 16, 64);
        se += __shfl_xor(se, 32, 64);
        if (lane < 16) s_sefp[((g2 << 2) + jt) << 4 | lane] = se;
    }
    __syncthreads();

    // ---- phase T: 16 waves = (g2 = wv>>3, kt2 = wv&7), 2 k-tiles each ----
    {
        const int g2 = wv >> 3, kt2 = wv & 7;
        const int bg = (b << 1) | g2;
        #pragma unroll
        for (int task = 0; task < 2; ++task) {
            const int k0 = ((task << 3) + kt2) << 4;
            v4f tacc = {0.f, 0.f, 0.f, 0.f};
            #pragma unroll
            for (int jc = 0; jc < 2; ++jc) {
                v8s aeh = *(const v8s*)&s_eh[g2 * 1152 + nn * 72 + (jc << 5) + (quad << 3)];
                v8s ael = *(const v8s*)&s_el[g2 * 1152 + nn * 72 + (jc << 5) + (quad << 3)];
                short bu[8];
                #pragma unroll
                for (int jj = 0; jj < 8; ++jj)
                    bu[jj] = s_U[((jc << 5) + (quad << 3) + jj) * 268 + k0 + nn];
                v8s bf = (v8s){bu[0], bu[1], bu[2], bu[3],
                               bu[4], bu[5], bu[6], bu[7]};
                tacc = __builtin_amdgcn_mfma_f32_16x16x32_bf16(aeh, bf, tacc, 0, 0, 0);
                tacc = __builtin_amdgcn_mfma_f32_16x16x32_bf16(ael, bf, tacc, 0, 0, 0);
            }
            #pragma unroll
            for (int r = 0; r < 4; ++r) {
                int i = (quad << 2) + r;
                tpart_out[(((((p << 6) + bg) << 4) + i) << 8) + k0 + nn] = tacc[r];
            }
        }
    }
    if (tid < 32) {
        int g2 = tid >> 4, i = tid & 15;
        float ss = 0.f;
        #pragma unroll
        for (int jt = 0; jt < 4; ++jt) ss += s_sefp[((g2 << 2) + jt) << 4 | i];
        sefpart_out[(p << 10) + (((b << 1) | g2) << 4) + i] = ss;
    }
}

// ---------------------------------------------------------------------------
extern "C" void kernel_launch(void* const* d_in, const int* in_sizes, int n_in,
                              void* d_out, int out_size, void* d_ws, size_t ws_size,
                              hipStream_t stream) {
    const float* U = (const float*)d_in[0];   // [32,1024,256]
    const float* W = (const float*)d_in[1];   // [256,2048]
    float* out = (float*)d_out;               // [32,32,64]
    float* ws = (float*)d_ws;

    float* t0p   = ws;                  // [32][16][256]      = 131,072
    float* WT    = t0p + 131072;        // [2048][256]        = 524,288
    float* bmatg = WT + 524288;         // [64][1024][16]     = 1,048,576
    float* tp    = bmatg + 1048576;     // [16][64][16][256]  = 4,194,304
    float* sefp  = tp + 4194304;        // [16][64][16]       = 16,384
    short* wbt_h = (short*)(sefp + 16384);  // [64][16][256] shorts
    short* wbt_l = wbt_h + 262144;

    k_init<<<640, 256, 0, stream>>>(U, W, t0p, WT);
    k_sv<<<1024, 256, 0, stream>>>(t0p, tp, sefp, W, WT,
                                   wbt_h, wbt_l, out, 0, 0);
    k_pass<<<512, 1024, 0, stream>>>(U, wbt_h, wbt_l, bmatg, tp, sefp, 0);
    k_sv<<<1024, 256, 0, stream>>>(t0p, tp, sefp, W, WT,
                                   wbt_h, wbt_l, out, 1, 0);
    k_pass<<<512, 1024, 0, stream>>>(U, wbt_h, wbt_l, bmatg, tp, sefp, 1);
    k_sv<<<1024, 256, 0, stream>>>(t0p, tp, sefp, W, WT,
                                   wbt_h, wbt_l, out, 1, 1);
}